// Round 14
// baseline (436.857 us; speedup 1.0000x reference)
//
#include <hip/hip_runtime.h>
#include <hip/hip_bf16.h>
#include <hip/hip_cooperative_groups.h>

namespace cg = cooperative_groups;

#define NSP 4096      // D*H*W
#define CH 256
#define NB 2
#define NG 8
#define CPG 32        // channels per group
#define NHD 4         // heads
#define HDIM 64       // head dim

typedef unsigned short u16;
typedef unsigned int u32;
typedef __attribute__((ext_vector_type(8))) short bf16x8;
typedef __attribute__((ext_vector_type(4))) float f32x4;

#define MFMA __builtin_amdgcn_mfma_f32_16x16x32_bf16
#define QSCALE 0.18033688f   // 0.125 * log2(e): folds attn scale + exp2 domain

__device__ __forceinline__ u16 f2bf(float f) {
    u32 i = __float_as_uint(f);
    u32 r = (i + 0x7FFFu + ((i >> 16) & 1u)) >> 16;   // round-nearest-even
    return (u16)r;
}

// async global->LDS DMA: wave loads 1 KB (16 B/lane); lds dst = uniform base + lane*16
__device__ __forceinline__ void dma16(const u16* g, u16* l) {
    __builtin_amdgcn_global_load_lds(
        (const __attribute__((address_space(1))) void*)g,
        (__attribute__((address_space(3))) void*)l, 16, 0, 0);
}

// =============== single cooperative kernel: 5 phases, grid.sync between ===============
// grid 256 x 512 (1 block/CU @ 128 KB LDS). Phase bodies = verified round-13 kernels.
__global__ __launch_bounds__(512, 2) void mega(
    const float* __restrict__ qw, const float* __restrict__ pw,
    u16* __restrict__ wqb, u16* __restrict__ wpb,
    const float* __restrict__ x, float* __restrict__ partial,
    const float* __restrict__ gnw, const float* __restrict__ gnb,
    u16* __restrict__ xnT, const float* __restrict__ qkvb,
    u16* __restrict__ qT, u16* __restrict__ kT, u16* __restrict__ vN,
    const float* __restrict__ projb, float* __restrict__ out) {
    cg::grid_group grid = cg::this_grid();
    __shared__ __align__(16) char LDS[131072];
    const int t = threadIdx.x;
    const int blk = blockIdx.x;
    const int half = t >> 8, t256 = t & 255;
    const int wave = t >> 6, lane = t & 63;
    u16* aoT = xnT;   // xnT dead after P3

    // ---------- P1: weight fp32->bf16 (XOR-chunk-swizzled rows) + GN partials ----------
    {
        int idx = blk * 512 + t;
        if (idx < (4 * CH * CH) / 4) {
            int i = idx * 4;
            const float* src; u16* dstbase; int j;
            if (i < 3 * CH * CH) { src = qw + i; dstbase = wqb; j = i; }
            else { j = i - 3 * CH * CH; src = pw + j; dstbase = wpb; }
            int m = j >> 8, c = j & 255;
            int dc = (((c >> 3) ^ (m & 7)) << 3) | (c & 7);
            float4 v = *(const float4*)src;
            ushort4 o;
            o.x = f2bf(v.x); o.y = f2bf(v.y); o.z = f2bf(v.z); o.w = f2bf(v.w);
            *(ushort4*)(dstbase + (m << 8) + dc) = o;
        }
        // GN partial: blk = bg*16 + chunk
        const float* p = x + (size_t)(blk >> 4) * (CPG * NSP) + (blk & 15) * 8192;
        float s = 0.f, ss = 0.f;
        for (int i = t; i < 2048; i += 512) {
            float4 u = ((const float4*)p)[i];
            s += u.x + u.y + u.z + u.w;
            ss += u.x * u.x + u.y * u.y + u.z * u.z + u.w * u.w;
        }
        for (int off = 32; off > 0; off >>= 1) {
            s += __shfl_down(s, off);
            ss += __shfl_down(ss, off);
        }
        float* red = (float*)LDS;
        if (lane == 0) { red[wave * 2] = s; red[wave * 2 + 1] = ss; }
        __syncthreads();
        if (t == 0) {
            float ts = 0.f, tq = 0.f;
#pragma unroll
            for (int wv = 0; wv < 8; ++wv) { ts += red[wv * 2]; tq += red[wv * 2 + 1]; }
            partial[blk * 2] = ts; partial[blk * 2 + 1] = tq;
        }
    }
    __threadfence();
    grid.sync();

    // ---------- P2: GroupNorm apply + transpose -> xnT[b][n][c] swizzled ----------
    {
        u16 (*T)[72] = (u16(*)[72])(LDS + half * 9216);
        int vb = blk * 2 + half;               // old grid (64,4,2)
        int n0 = (vb & 63) * 64;
        int c0 = ((vb >> 6) & 3) * 64;
        int bb = vb >> 8;
        int rc = t256 & 63;
        int g  = t256 >> 6;
        int c  = c0 + rc;
        int bg = bb * NG + c / CPG;
        float s = 0.f, q = 0.f;
#pragma unroll
        for (int j = 0; j < 16; ++j) {
            s += partial[(bg * 16 + j) * 2];
            q += partial[(bg * 16 + j) * 2 + 1];
        }
        const float cnt = (float)(CPG * NSP);
        float mean = s / cnt;
        float var  = q / cnt - mean * mean;
        float rstd = rsqrtf(var + 1e-5f);
        float wf = gnw[c] * rstd, bv = gnb[c] - mean * wf;
        const float* px = x + ((size_t)bb * CH + c) * NSP + n0 + g * 16;
#pragma unroll
        for (int i = 0; i < 4; ++i) {
            float4 v = *(const float4*)(px + i * 4);
            T[g * 16 + i * 4 + 0][rc] = f2bf(v.x * wf + bv);
            T[g * 16 + i * 4 + 1][rc] = f2bf(v.y * wf + bv);
            T[g * 16 + i * 4 + 2][rc] = f2bf(v.z * wf + bv);
            T[g * 16 + i * 4 + 3][rc] = f2bf(v.w * wf + bv);
        }
        __syncthreads();
        int n = t256 >> 2, ch = (t256 & 3) * 16;
        uint4 o0 = *(const uint4*)&T[n][ch];
        uint4 o1 = *(const uint4*)&T[n][ch + 8];
        const int sw = n & 7;
        const int chunk0 = (c0 + ch) >> 3;
        u16* rowp = xnT + ((size_t)bb * NSP + n0 + n) * CH;
        *(uint4*)(rowp + ((chunk0 ^ sw) << 3))       = o0;
        *(uint4*)(rowp + (((chunk0 + 1) ^ sw) << 3)) = o1;
    }
    __threadfence();
    grid.sync();

    // ---------- P3: LDS-staged MFMA GEMM QKV (3 tiles per virtual block) ----------
    {
        u16* As = (u16*)(LDS + half * 65536);
        u16* Bs = (u16*)(LDS + half * 65536 + 32768);
        const int wave4 = t256 >> 6;
        const int lq = lane & 15, quad = lane >> 4;
        for (int it = 0; it < 3; ++it) {
            int vb = (it * 256 + blk) * 2 + half;   // old grid (64,12,2)
            int vbx = vb & 63, rest = vb >> 6;
            int vby = rest % 12, bb = rest / 12;
            int n0 = vbx * 64, m0 = vby * 64;
            __syncthreads();   // WAR: previous tile's LDS reads complete
#pragma unroll
            for (int j = 0; j < 8; ++j) {
                int r2 = (wave4 * 8 + j) * 2;
                dma16(wqb + (size_t)(m0 + r2) * CH + lane * 8, As + r2 * 256);
                dma16(xnT + ((size_t)bb * NSP + n0 + r2) * CH + lane * 8, Bs + r2 * 256);
            }
            __syncthreads();   // drains DMA (vmcnt 0)
            const int wm = (wave4 >> 1) * 32, wn = (wave4 & 1) * 32;
            const int sw = lq & 7;
            f32x4 acc[2][2] = {};
#pragma unroll
            for (int kk = 0; kk < 8; ++kk) {
                bf16x8 a[2], b[2];
#pragma unroll
                for (int mt = 0; mt < 2; ++mt)
                    a[mt] = *(const bf16x8*)(As + (wm + mt * 16 + lq) * 256 +
                                             ((((kk * 4 + quad) ^ sw)) << 3));
#pragma unroll
                for (int nt = 0; nt < 2; ++nt)
                    b[nt] = *(const bf16x8*)(Bs + (wn + nt * 16 + lq) * 256 +
                                             ((((kk * 4 + quad) ^ sw)) << 3));
#pragma unroll
                for (int mt = 0; mt < 2; ++mt)
#pragma unroll
                    for (int nt = 0; nt < 2; ++nt)
                        acc[mt][nt] = MFMA(a[mt], b[nt], acc[mt][nt], 0, 0, 0);
            }
            const int sect = m0 >> 8;              // 0=Q, 1=K, 2=V
            const int h = (m0 & 255) >> 6;
            const float osc = (sect == 0) ? QSCALE : 1.f;
#pragma unroll
            for (int im = 0; im < 2; ++im) {
                int ml = wm + im * 16 + quad * 4;
                float4 bs = *(const float4*)(qkvb + m0 + ml);
#pragma unroll
                for (int in = 0; in < 2; ++in) {
                    int n = n0 + wn + in * 16 + lq;
                    f32x4 a = acc[im][in];
                    float v0 = (a[0] + bs.x) * osc, v1 = (a[1] + bs.y) * osc;
                    float v2 = (a[2] + bs.z) * osc, v3 = (a[3] + bs.w) * osc;
                    if (sect < 2) {
                        int lc = ml >> 3, sub = ml & 7;
                        int colp = ((lc ^ (n & 7)) << 3) | sub;   // XOR chunk swizzle
                        u16* base = (sect ? kT : qT) +
                                    (((size_t)bb * NHD + h) * NSP + n) * HDIM + colp;
                        ushort4 o;
                        o.x = f2bf(v0); o.y = f2bf(v1); o.z = f2bf(v2); o.w = f2bf(v3);
                        *(ushort4*)base = o;
                    } else {
                        float vv[4] = {v0, v1, v2, v3};
#pragma unroll
                        for (int r = 0; r < 4; ++r) {
                            int ch = (m0 - 512) + ml + r;
                            int pos = (n & ~63) + ((((n >> 3) & 7) ^ (ch & 7)) << 3) + (n & 7);
                            vN[((size_t)bb * CH + ch) * NSP + pos] = f2bf(vv[r]);
                        }
                    }
                }
            }
        }
    }
    __threadfence();
    grid.sync();

    // ---------- P4: attn10 (max-free exp2 softmax, deferred l) ----------
    {
        typedef u16 kvarr[2][64][64];
        kvarr* Ks = (kvarr*)LDS;                                  // [kh][buf][key][ch]
        kvarr* Vs = (kvarr*)(LDS + 32768);                        // [kh][buf][ch][key]
        u16 (*Ps)[32][72] = (u16(*)[32][72])(LDS + 65536);
        float (*Obuf)[32][68] = (float(*)[32][68])(LDS + 65536);  // aliases Ps
        float (*Ml)[2][16] = (float(*)[2][16])(LDS + 102400);

        const int qx = blk & 31, h = (blk >> 5) & 3, bb = blk >> 7;
        const int qg = wave & 3, kh = wave >> 2;
        const int lq = lane & 15, quad = lane >> 4;
        const int q_lo = qx * 128 + qg * 32;

        const int pr = quad ^ (lq & 7);
        const u16* qrow0 = qT + (((size_t)bb * NHD + h) * NSP + q_lo + lq) * HDIM;
        bf16x8 qf[2][2];
        qf[0][0] = *(const bf16x8*)(qrow0 + pr * 8);
        qf[0][1] = *(const bf16x8*)(qrow0 + (pr ^ 4) * 8);
        qf[1][0] = *(const bf16x8*)(qrow0 + 16 * HDIM + pr * 8);
        qf[1][1] = *(const bf16x8*)(qrow0 + 16 * HDIM + (pr ^ 4) * 8);

        const u16* khead = kT + ((size_t)bb * NHD + h) * NSP * (size_t)HDIM;
        const u16* vhead = vN + ((size_t)bb * CH + h * HDIM) * NSP;

        const int sK   = (wave < 4);
        const int kh_s = (wave >> 1) & 1;
        const int rbase = (wave & 1) * 32;
#pragma unroll
        for (int j = 0; j < 4; ++j) {
            int r8 = rbase + j * 8;
            if (sK) {
                dma16(khead + (size_t)(kh_s * 2048 + r8) * HDIM + lane * 8,
                      &Ks[kh_s][0][r8][0]);
            } else {
                dma16(vhead + (size_t)(r8 + (lane >> 3)) * NSP + kh_s * 2048 + (lane & 7) * 8,
                      &Vs[kh_s][0][r8][0]);
            }
        }

        float l[2] = {0.f, 0.f};
        f32x4 O[2][4] = {};
        for (int kt = 0; kt < 32; ++kt) {
            const int cur = kt & 1;
            __syncthreads();   // drains DMA (vmcnt 0) + buffer sync
            if (kt < 31) {
                const int K1 = (kt + 1) * 64;
#pragma unroll
                for (int j = 0; j < 4; ++j) {
                    int r8 = rbase + j * 8;
                    if (sK) {
                        dma16(khead + (size_t)(kh_s * 2048 + K1 + r8) * HDIM + lane * 8,
                              &Ks[kh_s][cur ^ 1][r8][0]);
                    } else {
                        dma16(vhead + (size_t)(r8 + (lane >> 3)) * NSP + kh_s * 2048 + K1 + (lane & 7) * 8,
                              &Vs[kh_s][cur ^ 1][r8][0]);
                    }
                }
            }
            f32x4 st[2][4];
#pragma unroll
            for (int mt = 0; mt < 4; ++mt) {
                bf16x8 a0 = *(const bf16x8*)&Ks[kh][cur][mt * 16 + lq][pr * 8];
                bf16x8 a1 = *(const bf16x8*)&Ks[kh][cur][mt * 16 + lq][(pr ^ 4) * 8];
#pragma unroll
                for (int qt = 0; qt < 2; ++qt) {
                    f32x4 acc = {0.f, 0.f, 0.f, 0.f};
                    acc = MFMA(a0, qf[qt][0], acc, 0, 0, 0);
                    acc = MFMA(a1, qf[qt][1], acc, 0, 0, 0);
                    st[qt][mt] = acc;
                }
            }
#pragma unroll
            for (int qt = 0; qt < 2; ++qt) {
                float sum = 0.f;
#pragma unroll
                for (int mt = 0; mt < 4; ++mt) {
                    float p0 = __builtin_amdgcn_exp2f(st[qt][mt][0]);
                    float p1 = __builtin_amdgcn_exp2f(st[qt][mt][1]);
                    float p2 = __builtin_amdgcn_exp2f(st[qt][mt][2]);
                    float p3 = __builtin_amdgcn_exp2f(st[qt][mt][3]);
                    sum += (p0 + p1) + (p2 + p3);
                    u32 r0 = __float_as_uint(p0) + 0x8000u;
                    u32 r1 = __float_as_uint(p1) + 0x8000u;
                    u32 r2 = __float_as_uint(p2) + 0x8000u;
                    u32 r3 = __float_as_uint(p3) + 0x8000u;
                    uint2 pkk;
                    pkk.x = __builtin_amdgcn_perm(r1, r0, 0x07060302);
                    pkk.y = __builtin_amdgcn_perm(r3, r2, 0x07060302);
                    *(uint2*)&Ps[wave][qt * 16 + lq][mt * 16 + quad * 4] = pkk;
                }
                l[qt] += sum;
            }
            bf16x8 pf[2][2];
            pf[0][0] = *(const bf16x8*)&Ps[wave][lq][quad * 8];
            pf[0][1] = *(const bf16x8*)&Ps[wave][lq][32 + quad * 8];
            pf[1][0] = *(const bf16x8*)&Ps[wave][16 + lq][quad * 8];
            pf[1][1] = *(const bf16x8*)&Ps[wave][16 + lq][32 + quad * 8];
#pragma unroll
            for (int mtc = 0; mtc < 4; ++mtc) {
                bf16x8 v0 = *(const bf16x8*)&Vs[kh][cur][mtc * 16 + lq][pr * 8];
                bf16x8 v1 = *(const bf16x8*)&Vs[kh][cur][mtc * 16 + lq][(pr ^ 4) * 8];
#pragma unroll
                for (int qt = 0; qt < 2; ++qt) {
                    O[qt][mtc] = MFMA(v0, pf[qt][0], O[qt][mtc], 0, 0, 0);
                    O[qt][mtc] = MFMA(v1, pf[qt][1], O[qt][mtc], 0, 0, 0);
                }
            }
        }
#pragma unroll
        for (int qt = 0; qt < 2; ++qt) {
            l[qt] += __shfl_xor(l[qt], 16);
            l[qt] += __shfl_xor(l[qt], 32);
        }
        if (lane < 16) { Ml[wave][0][lane] = l[0]; Ml[wave][1][lane] = l[1]; }
        __syncthreads();
        float gl[2];
        gl[0] = l[0] + Ml[wave ^ 4][0][lq];
        gl[1] = l[1] + Ml[wave ^ 4][1][lq];
        if (kh == 1) {
#pragma unroll
            for (int qt = 0; qt < 2; ++qt)
#pragma unroll
                for (int mtc = 0; mtc < 4; ++mtc)
                    *(f32x4*)&Obuf[qg][qt * 16 + lq][mtc * 16 + quad * 4] = O[qt][mtc];
        }
        __syncthreads();
        if (kh == 0) {
            const int sw = lq & 7;
#pragma unroll
            for (int qt = 0; qt < 2; ++qt) {
                float linv = 1.f / gl[qt];
                u16* rowp = aoT + ((size_t)bb * NSP + q_lo + qt * 16 + lq) * CH;
#pragma unroll
                for (int mtc = 0; mtc < 4; ++mtc) {
                    f32x4 sres = O[qt][mtc] +
                                 *(const f32x4*)&Obuf[qg][qt * 16 + lq][mtc * 16 + quad * 4];
                    ushort4 o;
                    o.x = f2bf(sres[0] * linv);
                    o.y = f2bf(sres[1] * linv);
                    o.z = f2bf(sres[2] * linv);
                    o.w = f2bf(sres[3] * linv);
                    int chunk = (h << 3) | (mtc << 1) | (quad >> 1);
                    int col = ((chunk ^ sw) << 3) | ((quad & 1) << 2);
                    *(ushort4*)(rowp + col) = o;
                }
            }
        }
    }
    __threadfence();
    grid.sync();

    // ---------- P5: LDS-staged MFMA GEMM proj (+bias +residual, fp32 out) ----------
    {
        u16* As = (u16*)(LDS + half * 65536);
        u16* Bs = (u16*)(LDS + half * 65536 + 32768);
        const int wave4 = t256 >> 6;
        const int lq = lane & 15, quad = lane >> 4;
        int vb = blk * 2 + half;                // old grid (64,4,2)
        int vbx = vb & 63, vby = (vb >> 6) & 3, bb = vb >> 8;
        int n0 = vbx * 64, m0 = vby * 64;
#pragma unroll
        for (int j = 0; j < 8; ++j) {
            int r2 = (wave4 * 8 + j) * 2;
            dma16(wpb + (size_t)(m0 + r2) * CH + lane * 8, As + r2 * 256);
            dma16(aoT + ((size_t)bb * NSP + n0 + r2) * CH + lane * 8, Bs + r2 * 256);
        }
        __syncthreads();
        const int wm = (wave4 >> 1) * 32, wn = (wave4 & 1) * 32;
        const int sw = lq & 7;
        f32x4 acc[2][2] = {};
#pragma unroll
        for (int kk = 0; kk < 8; ++kk) {
            bf16x8 a[2], b[2];
#pragma unroll
            for (int mt = 0; mt < 2; ++mt)
                a[mt] = *(const bf16x8*)(As + (wm + mt * 16 + lq) * 256 +
                                         ((((kk * 4 + quad) ^ sw)) << 3));
#pragma unroll
            for (int nt = 0; nt < 2; ++nt)
                b[nt] = *(const bf16x8*)(Bs + (wn + nt * 16 + lq) * 256 +
                                         ((((kk * 4 + quad) ^ sw)) << 3));
#pragma unroll
            for (int mt = 0; mt < 2; ++mt)
#pragma unroll
                for (int nt = 0; nt < 2; ++nt)
                    acc[mt][nt] = MFMA(a[mt], b[nt], acc[mt][nt], 0, 0, 0);
        }
#pragma unroll
        for (int im = 0; im < 2; ++im) {
            int ml = wm + im * 16 + quad * 4;
            float4 bs = *(const float4*)(projb + m0 + ml);
            float bsv[4] = {bs.x, bs.y, bs.z, bs.w};
#pragma unroll
            for (int in = 0; in < 2; ++in) {
                int n = n0 + wn + in * 16 + lq;
                f32x4 a = acc[im][in];
#pragma unroll
                for (int r = 0; r < 4; ++r) {
                    size_t idx = ((size_t)bb * CH + m0 + ml + r) * NSP + n;
                    out[idx] = a[r] + bsv[r] + x[idx];
                }
            }
        }
    }
}

extern "C" void kernel_launch(void* const* d_in, const int* in_sizes, int n_in,
                              void* d_out, int out_size, void* d_ws, size_t ws_size,
                              hipStream_t stream) {
    const float* x      = (const float*)d_in[0];
    const float* norm_w = (const float*)d_in[1];
    const float* norm_b = (const float*)d_in[2];
    const float* qkv_w  = (const float*)d_in[3];
    const float* qkv_b  = (const float*)d_in[4];
    const float* proj_w = (const float*)d_in[5];
    const float* proj_b = (const float*)d_in[6];
    float* out = (float*)d_out;

    char* w = (char*)d_ws;
    float* partial = (float*)w;                       // 4 KB (16x16x2 fp32)
    u16* wqb = (u16*)(w + 4096);                      // 384 KB (768x256 bf16, swizzled)
    u16* wpb = (u16*)(w + 4096 + 393216);             // 128 KB (256x256 bf16, swizzled)
    u16* xnT = (u16*)(w + 528384);                    // 4 MB [b][n][c] swizzled (aliased by aoT)
    u16* qT  = (u16*)(w + 528384 + 4194304);          // 4 MB [b][h][n][64] swizzled, pre-scaled
    u16* kT  = (u16*)(w + 528384 + 2 * 4194304);      // 4 MB [b][h][n][64] swizzled
    u16* v   = (u16*)(w + 528384 + 3 * 4194304);      // 4 MB [b][c][n] swizzled blocks
    u16* aoT = xnT; (void)aoT;

    void* args[] = {
        (void*)&qkv_w, (void*)&proj_w, (void*)&wqb, (void*)&wpb,
        (void*)&x, (void*)&partial, (void*)&norm_w, (void*)&norm_b,
        (void*)&xnT, (void*)&qkv_b, (void*)&qT, (void*)&kT, (void*)&v,
        (void*)&proj_b, (void*)&out
    };
    hipLaunchCooperativeKernel((const void*)mega, dim3(256), dim3(512),
                               args, 0, stream);
}

// Round 15
// 143.118 us; speedup vs baseline: 3.0524x; 3.0524x over previous
//
#include <hip/hip_runtime.h>
#include <hip/hip_bf16.h>

#define NSP 4096      // D*H*W
#define CH 256
#define NB 2
#define NG 8
#define CPG 32        // channels per group
#define NHD 4         // heads
#define HDIM 64       // head dim

typedef unsigned short u16;
typedef unsigned int u32;
typedef __attribute__((ext_vector_type(8))) short bf16x8;
typedef __attribute__((ext_vector_type(4))) float f32x4;

#define MFMA __builtin_amdgcn_mfma_f32_16x16x32_bf16
#define QSCALE 0.18033688f   // 0.125 * log2(e): folds attn scale + exp2 domain

__device__ __forceinline__ u16 f2bf(float f) {
    u32 i = __float_as_uint(f);
    u32 r = (i + 0x7FFFu + ((i >> 16) & 1u)) >> 16;   // round-nearest-even
    return (u16)r;
}

// async global->LDS DMA: wave loads 1 KB (16 B/lane); lds dst = uniform base + lane*16
__device__ __forceinline__ void dma16(const u16* g, u16* l) {
    __builtin_amdgcn_global_load_lds(
        (const __attribute__((address_space(1))) void*)g,
        (__attribute__((address_space(3))) void*)l, 16, 0, 0);
}

// ------- fused prep: weight fp32->bf16 (XOR-chunk-swizzled rows) + GN partials -------
// Weight rows [m][256] stored with 16B chunk c at position c^(m&7) -- makes the
// gemm kernels' DMA-staged LDS image conflict-minimal (same idiom as qT/kT).
__global__ __launch_bounds__(256) void prep(const float* __restrict__ qw,
                                            const float* __restrict__ pw,
                                            u16* __restrict__ wqb,
                                            u16* __restrict__ wpb,
                                            const float* __restrict__ x,
                                            float* __restrict__ partial) {
    if (blockIdx.x < 256) {
        int i = (blockIdx.x * 256 + threadIdx.x) * 4;
        const float* src; u16* dstbase; int j;
        if (i < 3 * CH * CH) { src = qw + i; dstbase = wqb; j = i; }
        else { j = i - 3 * CH * CH; src = pw + j; dstbase = wpb; }
        int m = j >> 8, c = j & 255;
        int dc = ((((c >> 3) ^ (m & 7)) << 3)) | (c & 7);
        float4 v = *(const float4*)src;
        ushort4 o;
        o.x = f2bf(v.x); o.y = f2bf(v.y); o.z = f2bf(v.z); o.w = f2bf(v.w);
        *(ushort4*)(dstbase + (m << 8) + dc) = o;
        return;
    }
    const int id = blockIdx.x - 256;
    const int bg = id >> 4, chunk = id & 15;
    const float* p = x + (size_t)bg * (CPG * NSP) + chunk * 8192;
    float s = 0.f, ss = 0.f;
    for (int i = threadIdx.x; i < 2048; i += 256) {   // 8192 floats
        float4 u = ((const float4*)p)[i];
        s += u.x + u.y + u.z + u.w;
        ss += u.x * u.x + u.y * u.y + u.z * u.z + u.w * u.w;
    }
    for (int off = 32; off > 0; off >>= 1) {
        s += __shfl_down(s, off);
        ss += __shfl_down(ss, off);
    }
    __shared__ float red[4][2];
    const int wv = threadIdx.x >> 6;
    if ((threadIdx.x & 63) == 0) { red[wv][0] = s; red[wv][1] = ss; }
    __syncthreads();
    if (threadIdx.x == 0) {
        float ts = red[0][0] + red[1][0] + red[2][0] + red[3][0];
        float tq = red[0][1] + red[1][1] + red[2][1] + red[3][1];
        partial[(bg * 16 + chunk) * 2]     = ts;
        partial[(bg * 16 + chunk) * 2 + 1] = tq;
    }
}

// ------- GroupNorm apply + transpose: x[b][c][n] fp32 -> xnT[b][n][c] bf16 -------
// xnT rows XOR-chunk-swizzled (chunk c at c^(n&7)) for gemm_qkv's DMA staging.
__global__ __launch_bounds__(256) void gn_apply_t(const float* __restrict__ x,
                                                  const float* __restrict__ partial,
                                                  const float* __restrict__ w,
                                                  const float* __restrict__ b,
                                                  u16* __restrict__ xnT) {
    __shared__ u16 T[64][72];   // [n][c], pitch 144 B
    const int n0 = blockIdx.x * 64, c0 = blockIdx.y * 64, bb = blockIdx.z;
    const int t = threadIdx.x;
    const int rc = t & 63;          // channel within tile
    const int g  = t >> 6;          // n-chunk group of 16
    const int c  = c0 + rc;
    const int bg = bb * NG + c / CPG;
    float s = 0.f, q = 0.f;
#pragma unroll
    for (int j = 0; j < 16; ++j) {
        s += partial[(bg * 16 + j) * 2];
        q += partial[(bg * 16 + j) * 2 + 1];
    }
    const float cnt = (float)(CPG * NSP);
    float mean = s / cnt;
    float var  = q / cnt - mean * mean;
    float rstd = rsqrtf(var + 1e-5f);
    float wf = w[c] * rstd, bv = b[c] - mean * wf;
    const float* px = x + ((size_t)bb * CH + c) * NSP + n0 + g * 16;
#pragma unroll
    for (int i = 0; i < 4; ++i) {
        float4 v = *(const float4*)(px + i * 4);
        T[g * 16 + i * 4 + 0][rc] = f2bf(v.x * wf + bv);
        T[g * 16 + i * 4 + 1][rc] = f2bf(v.y * wf + bv);
        T[g * 16 + i * 4 + 2][rc] = f2bf(v.z * wf + bv);
        T[g * 16 + i * 4 + 3][rc] = f2bf(v.w * wf + bv);
    }
    __syncthreads();
    int n = t >> 2, ch = (t & 3) * 16;
    uint4 o0 = *(const uint4*)&T[n][ch];
    uint4 o1 = *(const uint4*)&T[n][ch + 8];
    const int sw = n & 7;
    const int chunk0 = (c0 + ch) >> 3;
    u16* rowp = xnT + ((size_t)bb * NSP + n0 + n) * CH;
    *(uint4*)(rowp + ((chunk0 ^ sw) << 3))       = o0;
    *(uint4*)(rowp + (((chunk0 + 1) ^ sw) << 3)) = o1;
}

// ------- LDS-staged MFMA GEMM QKV: Y[m][n] = sum_c Aw[m][c]*xnT[n][c] + bias -------
// K=256 staged entirely: A-panel 64x256 + B-panel 64x256 = 64 KB via DMA, one
// barrier, pure LDS-fed MFMA. 2 blocks/CU. Inputs pre-swizzled by producers.
__global__ __launch_bounds__(256, 2) void gemm_qkv(const u16* __restrict__ Aw,
                                                   const float* __restrict__ bias,
                                                   const u16* __restrict__ xnT,
                                                   u16* __restrict__ qT,
                                                   u16* __restrict__ kT,
                                                   u16* __restrict__ v) {
    __shared__ u16 As[64][256];
    __shared__ u16 Bs[64][256];
    const int n0 = blockIdx.x * 64, m0 = blockIdx.y * 64, bb = blockIdx.z;
    const int wave = threadIdx.x >> 6, lane = threadIdx.x & 63;
    const int lq = lane & 15, quad = lane >> 4;
#pragma unroll
    for (int j = 0; j < 8; ++j) {       // 32 row-pairs (1 KB each) per array
        int r2 = (wave * 8 + j) * 2;
        dma16(Aw + (size_t)(m0 + r2) * CH + lane * 8, &As[r2][0]);
        dma16(xnT + ((size_t)bb * NSP + n0 + r2) * CH + lane * 8, &Bs[r2][0]);
    }
    __syncthreads();
    const int wm = (wave >> 1) * 32, wn = (wave & 1) * 32;
    const int sw = lq & 7;
    f32x4 acc[2][2] = {};
#pragma unroll
    for (int kk = 0; kk < 8; ++kk) {
        bf16x8 a[2], b[2];
#pragma unroll
        for (int mt = 0; mt < 2; ++mt)
            a[mt] = *(const bf16x8*)&As[wm + mt * 16 + lq][(((kk * 4 + quad) ^ sw)) << 3];
#pragma unroll
        for (int nt = 0; nt < 2; ++nt)
            b[nt] = *(const bf16x8*)&Bs[wn + nt * 16 + lq][(((kk * 4 + quad) ^ sw)) << 3];
#pragma unroll
        for (int mt = 0; mt < 2; ++mt)
#pragma unroll
            for (int nt = 0; nt < 2; ++nt)
                acc[mt][nt] = MFMA(a[mt], b[nt], acc[mt][nt], 0, 0, 0);
    }
    const int sect = m0 >> 8;              // 0=Q, 1=K, 2=V
    const int h = (m0 & 255) >> 6;         // head for Q/K sections
    const float osc = (sect == 0) ? QSCALE : 1.f;
#pragma unroll
    for (int im = 0; im < 2; ++im) {
        int ml = wm + im * 16 + quad * 4;  // +r, local m in [0,64)
        float4 bs = *(const float4*)(bias + m0 + ml);
#pragma unroll
        for (int in = 0; in < 2; ++in) {
            int n = n0 + wn + in * 16 + lq;
            f32x4 a = acc[im][in];
            float v0 = (a[0] + bs.x) * osc, v1 = (a[1] + bs.y) * osc;
            float v2 = (a[2] + bs.z) * osc, v3 = (a[3] + bs.w) * osc;
            if (sect < 2) {
                int lc = ml >> 3, sub = ml & 7;
                int colp = ((lc ^ (n & 7)) << 3) | sub;   // XOR chunk swizzle
                u16* base = (sect ? kT : qT) +
                            (((size_t)bb * NHD + h) * NSP + n) * HDIM + colp;
                ushort4 o;
                o.x = f2bf(v0); o.y = f2bf(v1); o.z = f2bf(v2); o.w = f2bf(v3);
                *(ushort4*)base = o;
            } else {
                float vv[4] = {v0, v1, v2, v3};
#pragma unroll
                for (int r = 0; r < 4; ++r) {
                    int ch = (m0 - 512) + ml + r;
                    // swizzle within the aligned 64-key block, keyed by ch&7
                    int pos = (n & ~63) + ((((n >> 3) & 7) ^ (ch & 7)) << 3) + (n & 7);
                    v[((size_t)bb * CH + ch) * NSP + pos] = f2bf(vv[r]);
                }
            }
        }
    }
}

// ---------------- attn10: max-free exp2 softmax, deferred l-reduction ----------------
// (verified round 12/13) epilogue writes aoT XOR-chunk-swizzled for gemm_proj.
__global__ __launch_bounds__(512, 2) void attn10(const u16* __restrict__ qT,
                                                 const u16* __restrict__ kT,
                                                 const u16* __restrict__ vN,
                                                 u16* __restrict__ aoT) {
    __shared__ u16 Ks[2][2][64][64];   // [khalf][buf][key][ch-swizzled]  32 KB
    __shared__ u16 Vs[2][2][64][64];   // [khalf][buf][ch][key-swizzled]  32 KB
    __shared__ __align__(16) char smem_ps[8 * 32 * 72 * 2];   // Ps / Obuf alias
    __shared__ float Ml[8][2][16];     // [wave][qt][lq] = half-l
    u16 (*Ps)[32][72] = reinterpret_cast<u16(*)[32][72]>(smem_ps);
    float (*Obuf)[32][68] = reinterpret_cast<float(*)[32][68]>(smem_ps);

    const int h = blockIdx.y, bb = blockIdx.z;
    const int t = threadIdx.x;
    const int wave = t >> 6, lane = t & 63;
    const int qg = wave & 3, kh = wave >> 2;
    const int lq = lane & 15, quad = lane >> 4;
    const int q_lo = blockIdx.x * 128 + qg * 32;

    // Q fragments (swizzled global layout, pre-scaled by QSCALE), two q-tiles
    const int pr = quad ^ (lq & 7);
    const u16* qrow0 = qT + (((size_t)bb * NHD + h) * NSP + q_lo + lq) * HDIM;
    bf16x8 qf[2][2];
    qf[0][0] = *(const bf16x8*)(qrow0 + pr * 8);
    qf[0][1] = *(const bf16x8*)(qrow0 + (pr ^ 4) * 8);
    qf[1][0] = *(const bf16x8*)(qrow0 + 16 * HDIM + pr * 8);
    qf[1][1] = *(const bf16x8*)(qrow0 + 16 * HDIM + (pr ^ 4) * 8);

    const u16* khead = kT + ((size_t)bb * NHD + h) * NSP * (size_t)HDIM;
    const u16* vhead = vN + ((size_t)bb * CH + h * HDIM) * NSP;

    // per-wave staging role: waves 0-3 stage K (kh_s = wave>>1), 4-7 stage V
    const int sK   = (wave < 4);
    const int kh_s = (wave >> 1) & 1;
    const int rbase = (wave & 1) * 32;
    // prologue: DMA tile 0 into buf 0
    {
#pragma unroll
        for (int j = 0; j < 4; ++j) {
            int r8 = rbase + j * 8;
            if (sK) {
                dma16(khead + (size_t)(kh_s * 2048 + r8) * HDIM + lane * 8,
                      &Ks[kh_s][0][r8][0]);
            } else {
                dma16(vhead + (size_t)(r8 + (lane >> 3)) * NSP + kh_s * 2048 + (lane & 7) * 8,
                      &Vs[kh_s][0][r8][0]);
            }
        }
    }

    float l[2] = {0.f, 0.f};
    f32x4 O[2][4] = {};
    for (int kt = 0; kt < 32; ++kt) {
        const int cur = kt & 1;
        __syncthreads();   // drains this wave's DMA (vmcnt 0) + syncs buffers
        if (kt < 31) {     // DMA tile kt+1 into buf cur^1, overlaps compute
            const int K1 = (kt + 1) * 64;
#pragma unroll
            for (int j = 0; j < 4; ++j) {
                int r8 = rbase + j * 8;
                if (sK) {
                    dma16(khead + (size_t)(kh_s * 2048 + K1 + r8) * HDIM + lane * 8,
                          &Ks[kh_s][cur ^ 1][r8][0]);
                } else {
                    dma16(vhead + (size_t)(r8 + (lane >> 3)) * NSP + kh_s * 2048 + K1 + (lane & 7) * 8,
                          &Vs[kh_s][cur ^ 1][r8][0]);
                }
            }
        }
        // S^T[key][q] (exp2-domain scores) for both q-tiles
        f32x4 st[2][4];
#pragma unroll
        for (int mt = 0; mt < 4; ++mt) {
            bf16x8 a0 = *(const bf16x8*)&Ks[kh][cur][mt * 16 + lq][pr * 8];
            bf16x8 a1 = *(const bf16x8*)&Ks[kh][cur][mt * 16 + lq][(pr ^ 4) * 8];
#pragma unroll
            for (int qt = 0; qt < 2; ++qt) {
                f32x4 acc = {0.f, 0.f, 0.f, 0.f};
                acc = MFMA(a0, qf[qt][0], acc, 0, 0, 0);
                acc = MFMA(a1, qf[qt][1], acc, 0, 0, 0);
                st[qt][mt] = acc;
            }
        }
        // max-free softmax numerator: p = exp2(s), accumulate l per lane
#pragma unroll
        for (int qt = 0; qt < 2; ++qt) {
            float sum = 0.f;
#pragma unroll
            for (int mt = 0; mt < 4; ++mt) {
                float p0 = __builtin_amdgcn_exp2f(st[qt][mt][0]);
                float p1 = __builtin_amdgcn_exp2f(st[qt][mt][1]);
                float p2 = __builtin_amdgcn_exp2f(st[qt][mt][2]);
                float p3 = __builtin_amdgcn_exp2f(st[qt][mt][3]);
                sum += (p0 + p1) + (p2 + p3);
                // fast pack: round-half-up + v_perm pair-pack
                u32 r0 = __float_as_uint(p0) + 0x8000u;
                u32 r1 = __float_as_uint(p1) + 0x8000u;
                u32 r2 = __float_as_uint(p2) + 0x8000u;
                u32 r3 = __float_as_uint(p3) + 0x8000u;
                uint2 pkk;
                pkk.x = __builtin_amdgcn_perm(r1, r0, 0x07060302);
                pkk.y = __builtin_amdgcn_perm(r3, r2, 0x07060302);
                *(uint2*)&Ps[wave][qt * 16 + lq][mt * 16 + quad * 4] = pkk;
            }
            l[qt] += sum;
        }
        // PV: each Vs frag feeds 2 MFMAs (no rescale -- fixed shift)
        bf16x8 pf[2][2];
        pf[0][0] = *(const bf16x8*)&Ps[wave][lq][quad * 8];
        pf[0][1] = *(const bf16x8*)&Ps[wave][lq][32 + quad * 8];
        pf[1][0] = *(const bf16x8*)&Ps[wave][16 + lq][quad * 8];
        pf[1][1] = *(const bf16x8*)&Ps[wave][16 + lq][32 + quad * 8];
#pragma unroll
        for (int mtc = 0; mtc < 4; ++mtc) {
            bf16x8 v0 = *(const bf16x8*)&Vs[kh][cur][mtc * 16 + lq][pr * 8];
            bf16x8 v1 = *(const bf16x8*)&Vs[kh][cur][mtc * 16 + lq][(pr ^ 4) * 8];
#pragma unroll
            for (int qt = 0; qt < 2; ++qt) {
                O[qt][mtc] = MFMA(v0, pf[qt][0], O[qt][mtc], 0, 0, 0);
                O[qt][mtc] = MFMA(v1, pf[qt][1], O[qt][mtc], 0, 0, 0);
            }
        }
    }
    // ---- one-time l reduction (cross-quad) + 2-way key-half merge (plain adds) ----
#pragma unroll
    for (int qt = 0; qt < 2; ++qt) {
        l[qt] += __shfl_xor(l[qt], 16);
        l[qt] += __shfl_xor(l[qt], 32);
    }
    if (lane < 16) { Ml[wave][0][lane] = l[0]; Ml[wave][1][lane] = l[1]; }
    __syncthreads();   // Ml visible; all Ps reads done -> Obuf alias safe
    float gl[2];
    gl[0] = l[0] + Ml[wave ^ 4][0][lq];
    gl[1] = l[1] + Ml[wave ^ 4][1][lq];
    if (kh == 1) {
#pragma unroll
        for (int qt = 0; qt < 2; ++qt)
#pragma unroll
            for (int mtc = 0; mtc < 4; ++mtc)
                *(f32x4*)&Obuf[qg][qt * 16 + lq][mtc * 16 + quad * 4] = O[qt][mtc];
    }
    __syncthreads();
    if (kh == 0) {
        const int sw = lq & 7;
#pragma unroll
        for (int qt = 0; qt < 2; ++qt) {
            float linv = 1.f / gl[qt];
            u16* rowp = aoT + ((size_t)bb * NSP + q_lo + qt * 16 + lq) * CH;
#pragma unroll
            for (int mtc = 0; mtc < 4; ++mtc) {
                f32x4 sres = O[qt][mtc] +
                             *(const f32x4*)&Obuf[qg][qt * 16 + lq][mtc * 16 + quad * 4];
                ushort4 o;
                o.x = f2bf(sres[0] * linv);
                o.y = f2bf(sres[1] * linv);
                o.z = f2bf(sres[2] * linv);
                o.w = f2bf(sres[3] * linv);
                int chunk = (h << 3) | (mtc << 1) | (quad >> 1);
                int col = ((chunk ^ sw) << 3) | ((quad & 1) << 2);
                *(ushort4*)(rowp + col) = o;
            }
        }
    }
}

// ------- LDS-staged MFMA GEMM proj: out = Pw.aoT + bias + x (fp32 epilogue) -------
__global__ __launch_bounds__(256, 2) void gemm_proj(const u16* __restrict__ Aw,
                                                    const float* __restrict__ bias,
                                                    const u16* __restrict__ aoT,
                                                    const float* __restrict__ xres,
                                                    float* __restrict__ out) {
    __shared__ u16 As[64][256];
    __shared__ u16 Bs[64][256];
    const int n0 = blockIdx.x * 64, m0 = blockIdx.y * 64, bb = blockIdx.z;
    const int wave = threadIdx.x >> 6, lane = threadIdx.x & 63;
    const int lq = lane & 15, quad = lane >> 4;
#pragma unroll
    for (int j = 0; j < 8; ++j) {
        int r2 = (wave * 8 + j) * 2;
        dma16(Aw + (size_t)(m0 + r2) * CH + lane * 8, &As[r2][0]);
        dma16(aoT + ((size_t)bb * NSP + n0 + r2) * CH + lane * 8, &Bs[r2][0]);
    }
    __syncthreads();
    const int wm = (wave >> 1) * 32, wn = (wave & 1) * 32;
    const int sw = lq & 7;
    f32x4 acc[2][2] = {};
#pragma unroll
    for (int kk = 0; kk < 8; ++kk) {
        bf16x8 a[2], b[2];
#pragma unroll
        for (int mt = 0; mt < 2; ++mt)
            a[mt] = *(const bf16x8*)&As[wm + mt * 16 + lq][(((kk * 4 + quad) ^ sw)) << 3];
#pragma unroll
        for (int nt = 0; nt < 2; ++nt)
            b[nt] = *(const bf16x8*)&Bs[wn + nt * 16 + lq][(((kk * 4 + quad) ^ sw)) << 3];
#pragma unroll
        for (int mt = 0; mt < 2; ++mt)
#pragma unroll
            for (int nt = 0; nt < 2; ++nt)
                acc[mt][nt] = MFMA(a[mt], b[nt], acc[mt][nt], 0, 0, 0);
    }
#pragma unroll
    for (int im = 0; im < 2; ++im) {
        int ml = wm + im * 16 + quad * 4;
        float4 bs = *(const float4*)(bias + m0 + ml);
        float bsv[4] = {bs.x, bs.y, bs.z, bs.w};
#pragma unroll
        for (int in = 0; in < 2; ++in) {
            int n = n0 + wn + in * 16 + lq;
            f32x4 a = acc[im][in];
#pragma unroll
            for (int r = 0; r < 4; ++r) {
                size_t idx = ((size_t)bb * CH + m0 + ml + r) * NSP + n;
                out[idx] = a[r] + bsv[r] + xres[idx];
            }
        }
    }
}

extern "C" void kernel_launch(void* const* d_in, const int* in_sizes, int n_in,
                              void* d_out, int out_size, void* d_ws, size_t ws_size,
                              hipStream_t stream) {
    const float* x      = (const float*)d_in[0];
    const float* norm_w = (const float*)d_in[1];
    const float* norm_b = (const float*)d_in[2];
    const float* qkv_w  = (const float*)d_in[3];
    const float* qkv_b  = (const float*)d_in[4];
    const float* proj_w = (const float*)d_in[5];
    const float* proj_b = (const float*)d_in[6];
    float* out = (float*)d_out;

    char* w = (char*)d_ws;
    float* partial = (float*)w;                       // 4 KB (16x16x2 fp32)
    u16* wqb = (u16*)(w + 4096);                      // 384 KB (768x256 bf16, swizzled)
    u16* wpb = (u16*)(w + 4096 + 393216);             // 128 KB (256x256 bf16, swizzled)
    u16* xnT = (u16*)(w + 528384);                    // 4 MB [b][n][c] swizzled (aliased by aoT)
    u16* qT  = (u16*)(w + 528384 + 4194304);          // 4 MB [b][h][n][64] swizzled, pre-scaled
    u16* kT  = (u16*)(w + 528384 + 2 * 4194304);      // 4 MB [b][h][n][64] swizzled
    u16* v   = (u16*)(w + 528384 + 3 * 4194304);      // 4 MB [b][c][n] swizzled blocks
    u16* aoT = xnT;                                   // xnT dead after gemm_qkv

    prep<<<dim3(512), 256, 0, stream>>>(qkv_w, proj_w, wqb, wpb, x, partial);
    gn_apply_t<<<dim3(NSP / 64, CH / 64, NB), 256, 0, stream>>>(
        x, partial, norm_w, norm_b, xnT);
    gemm_qkv<<<dim3(NSP / 64, (3 * CH) / 64, NB), 256, 0, stream>>>(
        wqb, qkv_b, xnT, qT, kT, v);
    attn10<<<dim3(NSP / 128, NHD, NB), 512, 0, stream>>>(qT, kT, v, aoT);
    gemm_proj<<<dim3(NSP / 64, CH / 64, NB), 256, 0, stream>>>(
        wpb, proj_b, aoT, x, out);
}